// Round 1
// baseline (81.330 us; speedup 1.0000x reference)
//
#include <hip/hip_runtime.h>
#include <hip/hip_bf16.h>
#include <math.h>

// ROI adaptive max-pool to 7x7 (torch adaptive_max_pool2d bin semantics).
// feature_map: [B=2, C=256, H=50, W=50] fp32
// rois:        [R, 5] int32 (batch, x1, y1, x2, y2), 1<=w,h and x2<=W, y2<=H
// out:         [R, C, 7, 7] fp32
//
// One thread per output element. Output index (r, c, oy, ox) with ox
// innermost -> fully coalesced stores; loads walk contiguous rows of the
// ROI (L2/L3 resident: fm is only 5.12 MB).

#define OUT_N 7

__global__ __launch_bounds__(256) void roicrop_kernel(
    const float* __restrict__ fm,
    const int* __restrict__ rois,
    float* __restrict__ out,
    int R, int C, int H, int W)
{
    int idx = blockIdx.x * blockDim.x + threadIdx.x;
    int total = R * C * OUT_N * OUT_N;
    if (idx >= total) return;

    int j = idx % OUT_N;
    int t = idx / OUT_N;
    int i = t % OUT_N;
    t /= OUT_N;
    int c = t % C;
    int r = t / C;

    const int* roi = rois + r * 5;
    int b  = roi[0];
    int x1 = roi[1];
    int y1 = roi[2];
    int x2 = roi[3];
    int y2 = roi[4];
    int h = y2 - y1;
    int w = x2 - x1;

    // torch adaptive bins: start = floor(i*n/OUT), end = ceil((i+1)*n/OUT)
    int ys = y1 + (i * h) / OUT_N;
    int ye = y1 + ((i + 1) * h + OUT_N - 1) / OUT_N;
    int xs = x1 + (j * w) / OUT_N;
    int xe = x1 + ((j + 1) * w + OUT_N - 1) / OUT_N;

    const float* base = fm + ((size_t)(b * C + c)) * (size_t)(H * W);

    float m = -INFINITY;
    for (int y = ys; y < ye; ++y) {
        const float* rowp = base + (size_t)y * W;
        for (int x = xs; x < xe; ++x) {
            m = fmaxf(m, rowp[x]);
        }
    }
    out[idx] = m;
}

extern "C" void kernel_launch(void* const* d_in, const int* in_sizes, int n_in,
                              void* d_out, int out_size, void* d_ws, size_t ws_size,
                              hipStream_t stream)
{
    const float* fm  = (const float*)d_in[0];
    const int* rois  = (const int*)d_in[1];
    float* out       = (float*)d_out;

    const int R = in_sizes[1] / 5;                 // 192
    const int C = out_size / (R * OUT_N * OUT_N);  // 256
    const int H = 50;
    const int W = 50;

    int total = R * C * OUT_N * OUT_N;
    int block = 256;
    int grid = (total + block - 1) / block;
    roicrop_kernel<<<grid, block, 0, stream>>>(fm, rois, out, R, C, H, W);
}